// Round 7
// baseline (500.299 us; speedup 1.0000x reference)
//
#include <hip/hip_runtime.h>

// Attention with policy-softmax, MI355X (gfx950).
// Shapes: B=16, N=1024, C=768, H=12, hd=64.
// R7: attn software pipelining — K prefetched per 64-key half (8 uint4,
// single-buffer WAR), VT hoisted into reg arrays (vA before S-phase, vB after
// exp). Peak live ~168 regs <= 170 budget at 3 waves/EU (watch WRITE_SIZE).
// Grid swizzle + halved S-phase + no-max-subtract softmax from R6 retained.

#define NB 16
#define NN 1024
#define NC 768
#define NH 12
#define HD 64
#define NM (NB*NN)      // 16384
#define QKVC (3*NC)     // 2304
#define QSCALE 0.18033688011112042f   // 0.125 * log2(e)

typedef _Float16 f16;
typedef _Float16 f16x8 __attribute__((ext_vector_type(8)));
typedef _Float16 f16x4 __attribute__((ext_vector_type(4)));
typedef __fp16 fp16x2 __attribute__((ext_vector_type(2)));   // cvt_pkrtz native type
typedef float f32x4 __attribute__((ext_vector_type(4)));

__device__ inline f16x8 as_f16x8(uint4 u){
  union { uint4 u; f16x8 h; } v; v.u = u; return v.h;
}

// async global->LDS, 16B per lane; lds ptr must be wave-uniform (lane l lands at +l*16B)
__device__ inline void gl_lds16(const f16* g, f16* l){
  __builtin_amdgcn_global_load_lds(
      (const __attribute__((address_space(1))) void*)g,
      (__attribute__((address_space(3))) void*)l, 16, 0, 0);
}

// ---------------- fp32 -> f16 convert ----------------
__global__ void cvt_f32_f16(const float* __restrict__ in, f16* __restrict__ out, int n4){
  int i = blockIdx.x*blockDim.x + threadIdx.x;
  if (i < n4){
    float4 v = ((const float4*)in)[i];
    f16x4 h; h[0]=(f16)v.x; h[1]=(f16)v.y; h[2]=(f16)v.z; h[3]=(f16)v.w;
    ((f16x4*)out)[i] = h;
  }
}

// ---------------- QKV GEMM: [16384,768] x [2304,768]^T, 128x128 tile ----------------
__launch_bounds__(256)
__global__ void gemm_qkv(const f16* __restrict__ X, const f16* __restrict__ W,
                         f16* __restrict__ Q, f16* __restrict__ K, f16* __restrict__ VT){
  __shared__ f16 sA[128*32];   // 8 KB, row-major [row][k], stride 32
  __shared__ f16 sB[128*32];
  const int R0 = blockIdx.y*128, C0 = blockIdx.x*128;
  const int t = threadIdx.x;
  const int w = t >> 6, l = t & 63, quad = l >> 4, lr = l & 15;
  const int wr = w >> 1, wc = w & 1;
  const int row0 = t >> 2, kc0 = (t & 3)*8;
  f32x4 acc[4][4] = {};
  for (int bk = 0; bk < NC; bk += 32){
#pragma unroll
    for (int r = 0; r < 2; r++){
      int row = r*64 + row0;
      gl_lds16(X + (size_t)(R0 + row)*NC + bk + kc0, sA + r*2048 + w*512);
      gl_lds16(W + (size_t)(C0 + row)*NC + bk + kc0, sB + r*2048 + w*512);
    }
    __syncthreads();
    f16x8 af[4], bf[4];
#pragma unroll
    for (int mt = 0; mt < 4; mt++)
      af[mt] = as_f16x8(*(const uint4*)(sA + (wr*64 + mt*16 + lr)*32 + quad*8));
#pragma unroll
    for (int nt = 0; nt < 4; nt++)
      bf[nt] = as_f16x8(*(const uint4*)(sB + (wc*64 + nt*16 + lr)*32 + quad*8));
#pragma unroll
    for (int mt = 0; mt < 4; mt++)
#pragma unroll
      for (int nt = 0; nt < 4; nt++)
        acc[mt][nt] = __builtin_amdgcn_mfma_f32_16x16x32_f16(af[mt], bf[nt], acc[mt][nt], 0, 0, 0);
    __syncthreads();
  }
  // scatter into Q / K / V^T. type uniform per block (128 | 768).
  const int type = C0 / NC;
#pragma unroll
  for (int nt = 0; nt < 4; nt++){
    int colg = C0 + wc*64 + nt*16 + lr;
    int rem  = colg - type*NC;
    int hh = rem >> 6, d = rem & 63;
#pragma unroll
    for (int mt = 0; mt < 4; mt++)
#pragma unroll
      for (int i = 0; i < 4; i++){
        int row = R0 + wr*64 + mt*16 + quad*4 + i;
        int bb = row >> 10, np = row & 1023;
        int bh = bb*NH + hh;
        float a = acc[mt][nt][i];
        if (type == 0)      Q[(bh << 16) + (np << 6) + d] = (f16)(a * QSCALE);
        else if (type == 1) K[(bh << 16) + (np << 6) + d] = (f16)a;
        else                VT[(bh << 16) + (d << 10) + np] = (f16)a;
      }
  }
}

// ---------------- Vsum: column sums of V per (b,h) ----------------
__global__ void vsum_kernel(const f16* __restrict__ VT, float* __restrict__ vsum){
  int bh = blockIdx.x;
  int t = threadIdx.x;
  int row = t >> 2, part = t & 3;
  const uint4* p = (const uint4*)(VT + ((size_t)bh << 16) + row*NN + part*256);
  float s = 0.f;
#pragma unroll
  for (int i = 0; i < 32; i++){
    f16x8 v = as_f16x8(p[i]);
#pragma unroll
    for (int j = 0; j < 8; j++) s += (float)v[j];
  }
  __shared__ float sR[64][4];
  sR[row][part] = s;
  __syncthreads();
  if (t < 64) vsum[bh*64 + t] = sR[t][0] + sR[t][1] + sR[t][2] + sR[t][3];
}

// ---------------- fused policy-softmax attention (pipelined) ----------------
// Grid: 1536 blocks; bh = blk % 192 (XCD swizzle), qt = blk / 192.
// 256 thr = 4 independent waves (32 queries each as two 16-q MFMA tiles).
// Per 128-key chunk: vA(VT s8=0,1) issued up front; S-phase in two 64-key
// halves with K-half prefetch (single-buffer); exp2 policy-softmax (no max
// subtract — exact via E=exp2(rowmax) epilogue fix); vB issued post-exp;
// PV + ones-MFMA row-sum. No barriers in the loop.
#define PSTR 136   // f16 row stride: 272B, 16B-aligned
__launch_bounds__(256, 3)
__global__ void attn_kernel(const f16* __restrict__ Q, const f16* __restrict__ K,
                            const f16* __restrict__ VT, const float* __restrict__ policy,
                            const float* __restrict__ vsum, f16* __restrict__ O){
  __shared__ f16 sP[4][2][16][PSTR];   // 34816 B
  __shared__ float sPol[1024];         // 4096 B

  const int blk = blockIdx.x;
  const int bh = blk % (NB*NH);        // stride-192 => same XCD for all qt of a bh
  const int qt = blk / (NB*NH);
  const int b = bh / NH;
  const size_t base = (size_t)bh << 16;

  const int t = threadIdx.x;
  const int w = t >> 6, l = t & 63, quad = l >> 4, lr = l & 15;
  const int q0 = qt*128 + w*32;
  const int qrow = q0 + lr;
  const int h = bh - b*NH;

  *(float4*)&sPol[t*4] = *(const float4*)(policy + b*NN + t*4);

  // Q fragments (pre-scaled), contiguous 16B global reads
  f16x8 qf[2][2];
#pragma unroll
  for (int tq = 0; tq < 2; tq++)
#pragma unroll
    for (int hf = 0; hf < 2; hf++)
      qf[tq][hf] = as_f16x8(*(const uint4*)(Q + base + (size_t)(q0 + tq*16 + lr)*HD + hf*32 + quad*8));

  float vs[4];
#pragma unroll
  for (int nt = 0; nt < 4; nt++) vs[nt] = vsum[bh*64 + nt*16 + lr];

  f16x8 ones;
#pragma unroll
  for (int j = 0; j < 8; j++) ones[j] = (f16)1.0f;

  float m_run[2] = {-INFINITY, -INFINITY};
  f32x4 acc_l[2] = {};
  f32x4 o[2][4] = {};

  const f16* Kl = K + base + (size_t)lr*HD + quad*8;   // lane-resolved K base

  // prefetch K half 0 (keys 0..63): kh[2*ct] = dims [q*8,+8), kh[2*ct+1] = +32
  uint4 kh[8];
#pragma unroll
  for (int ct = 0; ct < 4; ct++){
    kh[2*ct]   = *(const uint4*)(Kl + (size_t)(ct*16)*HD);
    kh[2*ct+1] = *(const uint4*)(Kl + (size_t)(ct*16)*HD + 32);
  }

  __syncthreads();   // sPol ready

  uint4 vA[8], vB[8];
#pragma unroll 1
  for (int c = 0; c < 8; c++){
    const int key0 = c*128;
    // ---- issue VT loads for s8=0,1 (consumed in PV; latency covered by S+exp)
#pragma unroll
    for (int s8 = 0; s8 < 2; s8++)
#pragma unroll
      for (int nt = 0; nt < 4; nt++)
        vA[s8*4 + nt] = *(const uint4*)(VT + base + (size_t)(nt*16 + lr)*NN + key0 + s8*32 + quad*8);

#pragma unroll
    for (int half = 0; half < 2; half++){
      // ---- S^T for this 64-key half from prefetched kh
      f32x4 accA[4], accB[4];
#pragma unroll
      for (int ct = 0; ct < 4; ct++){ accA[ct] = (f32x4){0,0,0,0}; accB[ct] = (f32x4){0,0,0,0}; }
#pragma unroll
      for (int ct = 0; ct < 4; ct++){
        f16x8 k0 = as_f16x8(kh[2*ct]);
        f16x8 k1 = as_f16x8(kh[2*ct+1]);
        accA[ct] = __builtin_amdgcn_mfma_f32_16x16x32_f16(k0, qf[0][0], accA[ct], 0, 0, 0);
        accA[ct] = __builtin_amdgcn_mfma_f32_16x16x32_f16(k1, qf[0][1], accA[ct], 0, 0, 0);
        accB[ct] = __builtin_amdgcn_mfma_f32_16x16x32_f16(k0, qf[1][0], accB[ct], 0, 0, 0);
        accB[ct] = __builtin_amdgcn_mfma_f32_16x16x32_f16(k1, qf[1][1], accB[ct], 0, 0, 0);
      }
      // ---- prefetch next K half (wraps to 0 at the end; WAR on kh is resolved
      // by the MFMA issues above — loads fill while exp below executes)
      {
        int gnext = ((c*2 + half + 1) & 15) * 64;
#pragma unroll
        for (int ct = 0; ct < 4; ct++){
          kh[2*ct]   = *(const uint4*)(Kl + (size_t)(gnext + ct*16)*HD);
          kh[2*ct+1] = *(const uint4*)(Kl + (size_t)(gnext + ct*16)*HD + 32);
        }
      }
      // ---- exp2 * policy -> sP (f16); local max tracking only
      float mA = m_run[0], mB = m_run[1];
      if (c != qt || half != (w >> 1)){
#pragma unroll
        for (int ct = 0; ct < 4; ct++){
          int kb = half*64 + ct*16 + quad*4;
          float4 pol4 = *(const float4*)&sPol[key0 + kb];
          const float* p4 = (const float*)&pol4;
          mA = fmaxf(mA, fmaxf(fmaxf(accA[ct][0], accA[ct][1]), fmaxf(accA[ct][2], accA[ct][3])));
          mB = fmaxf(mB, fmaxf(fmaxf(accB[ct][0], accB[ct][1]), fmaxf(accB[ct][2], accB[ct][3])));
          union { f16x4 v; fp16x2 hh[2]; } uA, uB;
          uA.hh[0] = __builtin_amdgcn_cvt_pkrtz(exp2f(accA[ct][0])*p4[0], exp2f(accA[ct][1])*p4[1]);
          uA.hh[1] = __builtin_amdgcn_cvt_pkrtz(exp2f(accA[ct][2])*p4[2], exp2f(accA[ct][3])*p4[3]);
          uB.hh[0] = __builtin_amdgcn_cvt_pkrtz(exp2f(accB[ct][0])*p4[0], exp2f(accB[ct][1])*p4[1]);
          uB.hh[1] = __builtin_amdgcn_cvt_pkrtz(exp2f(accB[ct][2])*p4[2], exp2f(accB[ct][3])*p4[3]);
          *(f16x4*)&sP[w][0][lr][kb] = uA.v;
          *(f16x4*)&sP[w][1][lr][kb] = uB.v;
        }
      } else {
#pragma unroll
        for (int ct = 0; ct < 4; ct++){
          int kb = half*64 + ct*16 + quad*4;
          float4 pol4 = *(const float4*)&sPol[key0 + kb];
          const float* p4 = (const float*)&pol4;
          float eA[4], eB[4];
#pragma unroll
          for (int i = 0; i < 4; i++){
            int kg = key0 + kb + i;
            float polA = (kg == qrow)      ? 1.0f : p4[i];
            float polB = (kg == qrow + 16) ? 1.0f : p4[i];
            mA = fmaxf(mA, accA[ct][i]); mB = fmaxf(mB, accB[ct][i]);
            eA[i] = exp2f(accA[ct][i]) * polA;
            eB[i] = exp2f(accB[ct][i]) * polB;
          }
          union { f16x4 v; fp16x2 hh[2]; } uA, uB;
          uA.hh[0] = __builtin_amdgcn_cvt_pkrtz(eA[0], eA[1]);
          uA.hh[1] = __builtin_amdgcn_cvt_pkrtz(eA[2], eA[3]);
          uB.hh[0] = __builtin_amdgcn_cvt_pkrtz(eB[0], eB[1]);
          uB.hh[1] = __builtin_amdgcn_cvt_pkrtz(eB[2], eB[3]);
          *(f16x4*)&sP[w][0][lr][kb] = uA.v;
          *(f16x4*)&sP[w][1][lr][kb] = uB.v;
        }
      }
      m_run[0] = mA; m_run[1] = mB;
    }

    // ---- issue VT loads for s8=2,3 (latency covered by PV s8=0,1)
#pragma unroll
    for (int s8 = 0; s8 < 2; s8++)
#pragma unroll
      for (int nt = 0; nt < 4; nt++)
        vB[s8*4 + nt] = *(const uint4*)(VT + base + (size_t)(nt*16 + lr)*NN + key0 + 64 + s8*32 + quad*8);

    // ---- O += P V^T ; l += P * ones (both MFMA)
#pragma unroll
    for (int s8 = 0; s8 < 4; s8++){
      f16x8 pfA = as_f16x8(*(const uint4*)&sP[w][0][lr][s8*32 + quad*8]);
      f16x8 pfB = as_f16x8(*(const uint4*)&sP[w][1][lr][s8*32 + quad*8]);
      acc_l[0] = __builtin_amdgcn_mfma_f32_16x16x32_f16(pfA, ones, acc_l[0], 0, 0, 0);
      acc_l[1] = __builtin_amdgcn_mfma_f32_16x16x32_f16(pfB, ones, acc_l[1], 0, 0, 0);
#pragma unroll
      for (int nt = 0; nt < 4; nt++){
        f16x8 vf = as_f16x8((s8 < 2 ? vA : vB)[(s8 & 1)*4 + nt]);
        o[0][nt] = __builtin_amdgcn_mfma_f32_16x16x32_f16(pfA, vf, o[0][nt], 0, 0, 0);
        o[1][nt] = __builtin_amdgcn_mfma_f32_16x16x32_f16(pfB, vf, o[1][nt], 0, 0, 0);
      }
    }
  }

  // ---- epilogue: out = (O + eps/N * E * Vsum) / (l + eps * E)
#pragma unroll
  for (int tq = 0; tq < 2; tq++){
    float mq = m_run[tq];
    mq = fmaxf(mq, __shfl_xor(mq, 16));
    mq = fmaxf(mq, __shfl_xor(mq, 32));   // per-query (lr) global max, all lanes
#pragma unroll
    for (int i = 0; i < 4; i++){
      float mi = __shfl(mq, quad*4 + i);  // max for query row quad*4+i
      float E  = exp2f(mi);
      float li = acc_l[tq][i];            // row-sum for this query
      float inv = 1.0f / (li + 1e-6f*E);
      float ec  = (1e-6f/1024.0f)*E;
      int row = q0 + tq*16 + quad*4 + i;
      f16* op = O + (size_t)(b*NN + row)*NC + h*HD;
#pragma unroll
      for (int nt = 0; nt < 4; nt++)
        op[nt*16 + lr] = (f16)((o[tq][nt][i] + ec*vs[nt]) * inv);
    }
  }
}

// ---------------- proj GEMM: [16384,768] x [768,768]^T + bias -> fp32, 128x128 ----------------
__launch_bounds__(256)
__global__ void gemm_proj(const f16* __restrict__ A, const f16* __restrict__ W,
                          const float* __restrict__ bias, float* __restrict__ out){
  __shared__ f16 sA[128*32];
  __shared__ f16 sB[128*32];
  const int R0 = blockIdx.y*128, C0 = blockIdx.x*128;
  const int t = threadIdx.x;
  const int w = t >> 6, l = t & 63, quad = l >> 4, lr = l & 15;
  const int wr = w >> 1, wc = w & 1;
  const int row0 = t >> 2, kc0 = (t & 3)*8;
  f32x4 acc[4][4] = {};
  for (int bk = 0; bk < NC; bk += 32){
#pragma unroll
    for (int r = 0; r < 2; r++){
      int row = r*64 + row0;
      gl_lds16(A + (size_t)(R0 + row)*NC + bk + kc0, sA + r*2048 + w*512);
      gl_lds16(W + (size_t)(C0 + row)*NC + bk + kc0, sB + r*2048 + w*512);
    }
    __syncthreads();
    f16x8 af[4], bf[4];
#pragma unroll
    for (int mt = 0; mt < 4; mt++)
      af[mt] = as_f16x8(*(const uint4*)(sA + (wr*64 + mt*16 + lr)*32 + quad*8));
#pragma unroll
    for (int nt = 0; nt < 4; nt++)
      bf[nt] = as_f16x8(*(const uint4*)(sB + (wc*64 + nt*16 + lr)*32 + quad*8));
#pragma unroll
    for (int mt = 0; mt < 4; mt++)
#pragma unroll
      for (int nt = 0; nt < 4; nt++)
        acc[mt][nt] = __builtin_amdgcn_mfma_f32_16x16x32_f16(af[mt], bf[nt], acc[mt][nt], 0, 0, 0);
    __syncthreads();
  }
#pragma unroll
  for (int nt = 0; nt < 4; nt++){
    int colg = C0 + wc*64 + nt*16 + lr;
    float bv = bias[colg];
#pragma unroll
    for (int mt = 0; mt < 4; mt++)
#pragma unroll
      for (int i = 0; i < 4; i++){
        int row = R0 + wr*64 + mt*16 + quad*4 + i;
        out[(size_t)row*NC + colg] = acc[mt][nt][i] + bv;
      }
  }
}

extern "C" void kernel_launch(void* const* d_in, const int* in_sizes, int n_in,
                              void* d_out, int out_size, void* d_ws, size_t ws_size,
                              hipStream_t stream) {
  const float* x      = (const float*)d_in[0];
  const float* policy = (const float*)d_in[1];
  const float* w_qkv  = (const float*)d_in[2];
  const float* w_proj = (const float*)d_in[3];
  const float* b_proj = (const float*)d_in[4];
  float* out = (float*)d_out;

  f16* x_h     = (f16*)d_ws;
  f16* wqkv_h  = x_h + (size_t)NM*NC;
  f16* wproj_h = wqkv_h + (size_t)QKVC*NC;
  f16* q_h     = wproj_h + (size_t)NC*NC;
  f16* k_h     = q_h + (size_t)NM*NC;
  f16* vt_h    = k_h + (size_t)NM*NC;
  float* vsum_f = (float*)(vt_h + (size_t)NM*NC);
  f16* attn_h  = x_h;   // x dead after gemm_qkv -> reuse

  cvt_f32_f16<<<(NM*NC/4 + 255)/256, 256, 0, stream>>>(x, x_h, NM*NC/4);
  cvt_f32_f16<<<(QKVC*NC/4 + 255)/256, 256, 0, stream>>>(w_qkv, wqkv_h, QKVC*NC/4);
  cvt_f32_f16<<<(NC*NC/4 + 255)/256, 256, 0, stream>>>(w_proj, wproj_h, NC*NC/4);

  gemm_qkv<<<dim3(QKVC/128, NM/128), 256, 0, stream>>>(x_h, wqkv_h, q_h, k_h, vt_h);

  vsum_kernel<<<dim3(NB*NH), 256, 0, stream>>>(vt_h, vsum_f);

  attn_kernel<<<dim3(NB*NH*(NN/128)), 256, 0, stream>>>(q_h, k_h, vt_h, policy, vsum_f, attn_h);

  gemm_proj<<<dim3(NC/128, NM/128), 256, 0, stream>>>(attn_h, wproj_h, b_proj, out);
}